// Round 1
// baseline (668.103 us; speedup 1.0000x reference)
//
#include <hip/hip_runtime.h>
#include <cstdint>

// CQAttention: B=32, D=128, Lc=2048, Lq=256, f32.
// Pipeline: cq/qq dots -> S GEMM -> row stats -> col stats (split+combine)
//           -> MT = S2^T @ Ct GEMM -> fused output (S1 rows, A, Bt, writes).
// Key algebraic rewrite: Bt = S1 @ (S2^T @ Ct)  (avoids Lc x Lc matrix).

#define NB 32
#define ND 128
#define NLC 2048
#define NLQ 256
#define FNEG (-1.0e30f)

// ---------------- cq / qq : out[g] = sum_d In[b,d,i] * w[d] ----------------
__global__ __launch_bounds__(256) void k_cq(const float* __restrict__ In,
                                            const float* __restrict__ w,
                                            float* __restrict__ outv, int L) {
  int g = blockIdx.x * 256 + threadIdx.x;
  int b = g / L, i = g - b * L;
  const float* p = In + (size_t)b * ND * L + i;
  float s = 0.f;
#pragma unroll 16
  for (int d = 0; d < ND; ++d) s = fmaf(p[(size_t)d * L], w[d], s);
  outv[g] = s;
}

// ---------------- S[b,i,j] = cq + qq + (C*w)^T Q + bias --------------------
__global__ __launch_bounds__(256) void k_S(const float* __restrict__ C,
                                           const float* __restrict__ Q,
                                           const float* __restrict__ w4mlu,
                                           const float* __restrict__ cq,
                                           const float* __restrict__ qq,
                                           const float* __restrict__ bias,
                                           float* __restrict__ S) {
  __shared__ float Cs[16][68];
  __shared__ float Qs[16][68];
  const int b = blockIdx.z;
  const int it = blockIdx.x * 64;
  const int jt = blockIdx.y * 64;
  const int tid = threadIdx.x;
  const int ti = tid >> 4, tj = tid & 15;
  const float* Cb = C + (size_t)b * ND * NLC + it;
  const float* Qb = Q + (size_t)b * ND * NLQ + jt;
  float acc[4][4] = {};
  for (int d0 = 0; d0 < ND; d0 += 16) {
#pragma unroll
    for (int k = 0; k < 4; ++k) {
      int idx = tid + k * 256;
      int dd = idx >> 6, col = idx & 63;
      Cs[dd][col] = Cb[(size_t)(d0 + dd) * NLC + col] * w4mlu[d0 + dd];
      Qs[dd][col] = Qb[(size_t)(d0 + dd) * NLQ + col];
    }
    __syncthreads();
#pragma unroll
    for (int dd = 0; dd < 16; ++dd) {
      float ca[4], qb[4];
      *(float4*)ca = *(const float4*)&Cs[dd][ti * 4];
      *(float4*)qb = *(const float4*)&Qs[dd][tj * 4];
#pragma unroll
      for (int a = 0; a < 4; ++a)
#pragma unroll
        for (int c = 0; c < 4; ++c) acc[a][c] = fmaf(ca[a], qb[c], acc[a][c]);
    }
    __syncthreads();
  }
  const float bv = bias[0];
  float* Sb = S + (size_t)b * NLC * NLQ;
#pragma unroll
  for (int a = 0; a < 4; ++a) {
    int i = it + ti * 4 + a;
    float base = cq[b * NLC + i] + bv;
    float o[4];
#pragma unroll
    for (int c = 0; c < 4; ++c) o[c] = acc[a][c] + base + qq[b * NLQ + jt + tj * 4 + c];
    *(float4*)&Sb[(size_t)i * NLQ + jt + tj * 4] = *(float4*)o;
  }
}

// ---------------- row stats: masked max/sum over j (Lq=256) ----------------
__global__ __launch_bounds__(256) void k_rowstats(const float* __restrict__ S,
                                                  const int* __restrict__ Qmask,
                                                  float* __restrict__ rowmax,
                                                  float* __restrict__ rowsum) {
  const int tid = threadIdx.x;
  const int wv = tid >> 6, lane = tid & 63;
  const int row = blockIdx.x * 4 + wv;  // [0, NB*NLC)
  const int b = row >> 11;              // / NLC
  const float* Sr = S + (size_t)row * NLQ;
  const int* Qm = Qmask + b * NLQ;
  float v[4];
#pragma unroll
  for (int k = 0; k < 4; ++k) {
    int j = lane + k * 64;
    float s = Sr[j];
    v[k] = Qm[j] ? s : s + FNEG;
  }
  float mx = fmaxf(fmaxf(v[0], v[1]), fmaxf(v[2], v[3]));
#pragma unroll
  for (int off = 32; off > 0; off >>= 1) mx = fmaxf(mx, __shfl_xor(mx, off, 64));
  float sum = 0.f;
#pragma unroll
  for (int k = 0; k < 4; ++k) sum += expf(v[k] - mx);
#pragma unroll
  for (int off = 32; off > 0; off >>= 1) sum += __shfl_xor(sum, off, 64);
  if (lane == 0) {
    rowmax[row] = mx;
    rowsum[row] = sum;
  }
}

// ---------------- col stats: partial online logsumexp over i chunks --------
__global__ __launch_bounds__(256) void k_colpart(const float* __restrict__ S,
                                                 const int* __restrict__ Cmask,
                                                 float* __restrict__ pm,
                                                 float* __restrict__ ps) {
  __shared__ float sm[4][64];
  __shared__ float ss[4][64];
  const int b = blockIdx.z;
  const int jt = blockIdx.x * 64;
  const int ic0 = blockIdx.y * (NLC / 8);
  const int tid = threadIdx.x;
  const int isub = tid >> 6, jl = tid & 63;
  const float* Sb = S + (size_t)b * NLC * NLQ + jt + jl;
  const int* Cm = Cmask + b * NLC;
  float m = -3.4e38f, sum = 0.f;
  for (int i = ic0 + isub; i < ic0 + NLC / 8; i += 4) {
    float s = Sb[(size_t)i * NLQ];
    float v = Cm[i] ? s : s + FNEG;
    float nm = fmaxf(m, v);
    sum = sum * expf(m - nm) + expf(v - nm);
    m = nm;
  }
  sm[isub][jl] = m;
  ss[isub][jl] = sum;
  __syncthreads();
  if (isub == 0) {
    float M = sm[0][jl], Sm = ss[0][jl];
#pragma unroll
    for (int k = 1; k < 4; ++k) {
      float m2 = sm[k][jl], s2 = ss[k][jl];
      float nm = fmaxf(M, m2);
      Sm = Sm * expf(M - nm) + s2 * expf(m2 - nm);
      M = nm;
    }
    int j = b * NLQ + jt + jl;
    pm[j * 8 + blockIdx.y] = M;
    ps[j * 8 + blockIdx.y] = Sm;
  }
}

__global__ __launch_bounds__(256) void k_colcombine(const float* __restrict__ pm,
                                                    const float* __restrict__ ps,
                                                    float* __restrict__ colmax,
                                                    float* __restrict__ colsum) {
  int g = blockIdx.x * 256 + threadIdx.x;  // [0, NB*NLQ)
  float M = -3.4e38f, Sm = 0.f;
#pragma unroll
  for (int k = 0; k < 8; ++k) {
    float m2 = pm[g * 8 + k], s2 = ps[g * 8 + k];
    float nm = fmaxf(M, m2);
    Sm = Sm * expf(M - nm) + s2 * expf(m2 - nm);
    M = nm;
  }
  colmax[g] = M;
  colsum[g] = Sm;
}

// ---------------- MT[b,d,q] = sum_i S2[i,q] * C[b,d,i] ---------------------
__global__ __launch_bounds__(256) void k_MT(const float* __restrict__ C,
                                            const float* __restrict__ S,
                                            const int* __restrict__ Cmask,
                                            const float* __restrict__ colmax,
                                            const float* __restrict__ colsum,
                                            float* __restrict__ MT) {
  __shared__ float As[16][68];
  __shared__ float Ps[16][68];
  const int b = blockIdx.z;
  const int dt = blockIdx.x * 64;
  const int qt = blockIdx.y * 64;
  const int tid = threadIdx.x;
  const int ti = tid >> 4, tj = tid & 15;
  const float* Cb = C + (size_t)b * ND * NLC;
  const float* Sb = S + (size_t)b * NLC * NLQ;
  const int* Cm = Cmask + b * NLC;
  const float* cmx = colmax + b * NLQ + qt;
  float acc[4][4] = {};
  for (int i0 = 0; i0 < NLC; i0 += 16) {
#pragma unroll
    for (int k = 0; k < 4; ++k) {
      int idx = tid + k * 256;
      int kk = idx & 15, dd = idx >> 4;
      As[kk][dd] = Cb[(size_t)(dt + dd) * NLC + i0 + kk];
    }
#pragma unroll
    for (int k = 0; k < 4; ++k) {
      int idx = tid + k * 256;
      int qq = idx & 63, kk = idx >> 6;
      int i = i0 + kk;
      float s = Sb[(size_t)i * NLQ + qt + qq];
      float v = Cm[i] ? s : s + FNEG;
      Ps[kk][qq] = expf(v - cmx[qq]);
    }
    __syncthreads();
#pragma unroll
    for (int kk = 0; kk < 16; ++kk) {
      float a4[4], p4[4];
      *(float4*)a4 = *(const float4*)&As[kk][ti * 4];
      *(float4*)p4 = *(const float4*)&Ps[kk][tj * 4];
#pragma unroll
      for (int a = 0; a < 4; ++a)
#pragma unroll
        for (int c = 0; c < 4; ++c) acc[a][c] = fmaf(a4[a], p4[c], acc[a][c]);
    }
    __syncthreads();
  }
  const float* csm = colsum + b * NLQ + qt;
  float inv[4];
#pragma unroll
  for (int c = 0; c < 4; ++c) inv[c] = 1.0f / csm[tj * 4 + c];
  float* Mb = MT + (size_t)b * ND * NLQ;
#pragma unroll
  for (int a = 0; a < 4; ++a) {
    float o[4];
#pragma unroll
    for (int c = 0; c < 4; ++c) o[c] = acc[a][c] * inv[c];
    *(float4*)&Mb[(size_t)(dt + ti * 4 + a) * NLQ + qt + tj * 4] = *(float4*)o;
  }
}

// ---------------- fused output ---------------------------------------------
__device__ __forceinline__ void phase_accum(const float* __restrict__ W,
                                            float (&acc)[4][4],
                                            float (&Ps)[32][260],
                                            float* __restrict__ Ws,
                                            int tid, int ti, int td) {
  for (int qc = 0; qc < NLQ; qc += 64) {
    __syncthreads();
#pragma unroll
    for (int k = 0; k < 32; ++k) {
      int idx = tid + k * 256;
      int qq = idx & 63, d = idx >> 6;
      Ws[d * 64 + (qq ^ (((d >> 2) & 15) << 2))] = W[(size_t)d * NLQ + qc + qq];
    }
    __syncthreads();
#pragma unroll
    for (int q0 = 0; q0 < 64; q0 += 4) {
      float p4[4][4], w4[4][4];
#pragma unroll
      for (int a = 0; a < 4; ++a)
        *(float4*)p4[a] = *(const float4*)&Ps[ti * 4 + a][qc + q0];
#pragma unroll
      for (int c = 0; c < 4; ++c) {
        int d = td * 4 + c;
        *(float4*)w4[c] = *(const float4*)&Ws[d * 64 + (q0 ^ (((d >> 2) & 15) << 2))];
      }
#pragma unroll
      for (int a = 0; a < 4; ++a)
#pragma unroll
        for (int c = 0; c < 4; ++c)
#pragma unroll
          for (int k2 = 0; k2 < 4; ++k2)
            acc[a][c] = fmaf(p4[a][k2], w4[c][k2], acc[a][c]);
    }
  }
}

__global__ __launch_bounds__(256) void k_out(const float* __restrict__ C,
                                             const float* __restrict__ Q,
                                             const float* __restrict__ S,
                                             const int* __restrict__ Qmask,
                                             const float* __restrict__ rowmax,
                                             const float* __restrict__ rowsum,
                                             const float* __restrict__ MT,
                                             float* __restrict__ out) {
  __shared__ float Ps[32][260];
  __shared__ float Ws[128 * 64];
  const int b = blockIdx.y;
  const int it = blockIdx.x * 32;
  const int tid = threadIdx.x;
  const int ti = tid >> 5, td = tid & 31;
  const float* Sb = S + ((size_t)b * NLC + it) * NLQ;
  const int* Qm = Qmask + b * NLQ;
  {
    const int q = tid;  // 256 threads cover all q
    const int qmv = Qm[q];
#pragma unroll 4
    for (int r = 0; r < 32; ++r) {
      float s = Sb[(size_t)r * NLQ + q];
      float v = qmv ? s : s + FNEG;
      int row = b * NLC + it + r;
      Ps[r][q] = expf(v - rowmax[row]) * (1.0f / rowsum[row]);
    }
  }
  float accA[4][4] = {};
  float accB[4][4] = {};
  const float* Qb = Q + (size_t)b * ND * NLQ;
  const float* Mb = MT + (size_t)b * ND * NLQ;
  phase_accum(Qb, accA, Ps, Ws, tid, ti, td);  // A = S1 @ Qt
  phase_accum(Mb, accB, Ps, Ws, tid, ti, td);  // Bt = S1 @ (S2^T Ct)

  const float* Cb = C + (size_t)b * ND * NLC + it + ti * 4;
  float* ob = out + (size_t)b * 4 * ND * NLC + it + ti * 4;
#pragma unroll
  for (int c = 0; c < 4; ++c) {
    int d = td * 4 + c;
    float ct[4];
    *(float4*)ct = *(const float4*)&Cb[(size_t)d * NLC];
    float av[4], cav[4], cbv[4];
#pragma unroll
    for (int a = 0; a < 4; ++a) {
      av[a] = accA[a][c];
      cav[a] = ct[a] * av[a];
      cbv[a] = ct[a] * accB[a][c];
    }
    *(float4*)&ob[(size_t)d * NLC] = *(float4*)ct;
    *(float4*)&ob[(size_t)(d + 128) * NLC] = *(float4*)av;
    *(float4*)&ob[(size_t)(d + 256) * NLC] = *(float4*)cav;
    *(float4*)&ob[(size_t)(d + 384) * NLC] = *(float4*)cbv;
  }
}

// ---------------------------------------------------------------------------
extern "C" void kernel_launch(void* const* d_in, const int* in_sizes, int n_in,
                              void* d_out, int out_size, void* d_ws, size_t ws_size,
                              hipStream_t stream) {
  const float* C = (const float*)d_in[0];
  const float* Q = (const float*)d_in[1];
  const int* Cmask = (const int*)d_in[2];
  const int* Qmask = (const int*)d_in[3];
  const float* w4C = (const float*)d_in[4];
  const float* w4Q = (const float*)d_in[5];
  const float* w4mlu = (const float*)d_in[6];
  const float* bias = (const float*)d_in[7];
  float* out = (float*)d_out;

  float* ws = (float*)d_ws;
  float* S = ws;
  float* rowmax = S + (size_t)NB * NLC * NLQ;
  float* rowsum = rowmax + NB * NLC;
  float* colmax = rowsum + NB * NLC;
  float* colsum = colmax + NB * NLQ;
  float* MT = colsum + NB * NLQ;
  float* cq = MT + (size_t)NB * ND * NLQ;
  float* qq = cq + NB * NLC;
  float* pm = qq + NB * NLQ;
  float* ps = pm + NB * NLQ * 8;
  size_t need = (size_t)(ps + NB * NLQ * 8 - ws) * sizeof(float);
  if (ws_size < need) return;  // fail loudly (output stays zero) rather than corrupt

  k_cq<<<NB * NLC / 256, 256, 0, stream>>>(C, w4C, cq, NLC);
  k_cq<<<NB * NLQ / 256, 256, 0, stream>>>(Q, w4Q, qq, NLQ);
  k_S<<<dim3(NLC / 64, NLQ / 64, NB), 256, 0, stream>>>(C, Q, w4mlu, cq, qq, bias, S);
  k_rowstats<<<NB * NLC / 4, 256, 0, stream>>>(S, Qmask, rowmax, rowsum);
  k_colpart<<<dim3(NLQ / 64, 8, NB), 256, 0, stream>>>(S, Cmask, pm, ps);
  k_colcombine<<<NB * NLQ / 256, 256, 0, stream>>>(pm, ps, colmax, colsum);
  k_MT<<<dim3(ND / 64, NLQ / 64, NB), 256, 0, stream>>>(C, S, Cmask, colmax, colsum, MT);
  k_out<<<dim3(NLC / 32, NB), 256, 0, stream>>>(C, Q, S, Qmask, rowmax, rowsum, MT, out);
}

// Round 2
// 470.111 us; speedup vs baseline: 1.4212x; 1.4212x over previous
//
#include <hip/hip_runtime.h>
#include <cstdint>

// CQAttention: B=32, D=128, Lc=2048, Lq=256, f32 in/out.
// Pipeline: cq/qq dots -> S GEMM -> row stats -> col stats -> MT = S2^T@Ct
//           -> fused MFMA output (A = S1@Qt, Bt = S1@MT, 4 write blocks).
// Bt = S1 @ (S2^T @ Ct) associativity rewrite avoids the Lc x Lc matrix.
// k_out uses bf16 MFMA: S rows and Q/MT panels are K(=j)-contiguous in
// memory, so A/B fragments load directly (no LDS in the main loop).

#define NB 32
#define ND 128
#define NLC 2048
#define NLQ 256
#define FNEG (-1.0e30f)

typedef __attribute__((ext_vector_type(8))) short bf16x8;
typedef __attribute__((ext_vector_type(4))) float f32x4;
#define MFMA16(a, b, c) __builtin_amdgcn_mfma_f32_16x16x32_bf16(a, b, c, 0, 0, 0)

__device__ __forceinline__ short f2bf(float x) {
  union { float f; unsigned u; } v; v.f = x;
  unsigned r = (v.u + 0x7FFFu + ((v.u >> 16) & 1u)) >> 16;
  return (short)r;
}

// ---------------- cq / qq : out[g] = sum_d In[b,d,i] * w[d] ----------------
__global__ __launch_bounds__(256) void k_cq(const float* __restrict__ In,
                                            const float* __restrict__ w,
                                            float* __restrict__ outv, int L) {
  int g = blockIdx.x * 256 + threadIdx.x;
  int b = g / L, i = g - b * L;
  const float* p = In + (size_t)b * ND * L + i;
  float s = 0.f;
#pragma unroll 16
  for (int d = 0; d < ND; ++d) s = fmaf(p[(size_t)d * L], w[d], s);
  outv[g] = s;
}

// ---------------- f32 -> bf16 bulk convert ---------------------------------
__global__ __launch_bounds__(256) void k_cvt(const float* __restrict__ in,
                                             short* __restrict__ outp) {
  int g = blockIdx.x * 256 + threadIdx.x;
  float4 v = *(const float4*)(in + (size_t)g * 4);
  short4 o;
  o.x = f2bf(v.x); o.y = f2bf(v.y); o.z = f2bf(v.z); o.w = f2bf(v.w);
  *(short4*)(outp + (size_t)g * 4) = o;
}

// ---------------- S[b,i,j] = cq + qq + (C*w)^T Q + bias --------------------
__global__ __launch_bounds__(256) void k_S(const float* __restrict__ C,
                                           const float* __restrict__ Q,
                                           const float* __restrict__ w4mlu,
                                           const float* __restrict__ cq,
                                           const float* __restrict__ qq,
                                           const float* __restrict__ bias,
                                           float* __restrict__ S) {
  __shared__ float Cs[16][68];
  __shared__ float Qs[16][68];
  const int b = blockIdx.z;
  const int it = blockIdx.x * 64;
  const int jt = blockIdx.y * 64;
  const int tid = threadIdx.x;
  const int ti = tid >> 4, tj = tid & 15;
  const float* Cb = C + (size_t)b * ND * NLC + it;
  const float* Qb = Q + (size_t)b * ND * NLQ + jt;
  float acc[4][4] = {};
  for (int d0 = 0; d0 < ND; d0 += 16) {
#pragma unroll
    for (int k = 0; k < 4; ++k) {
      int idx = tid + k * 256;
      int dd = idx >> 6, col = idx & 63;
      Cs[dd][col] = Cb[(size_t)(d0 + dd) * NLC + col] * w4mlu[d0 + dd];
      Qs[dd][col] = Qb[(size_t)(d0 + dd) * NLQ + col];
    }
    __syncthreads();
#pragma unroll
    for (int dd = 0; dd < 16; ++dd) {
      float ca[4], qb[4];
      *(float4*)ca = *(const float4*)&Cs[dd][ti * 4];
      *(float4*)qb = *(const float4*)&Qs[dd][tj * 4];
#pragma unroll
      for (int a = 0; a < 4; ++a)
#pragma unroll
        for (int c = 0; c < 4; ++c) acc[a][c] = fmaf(ca[a], qb[c], acc[a][c]);
    }
    __syncthreads();
  }
  const float bv = bias[0];
  float* Sb = S + (size_t)b * NLC * NLQ;
#pragma unroll
  for (int a = 0; a < 4; ++a) {
    int i = it + ti * 4 + a;
    float base = cq[b * NLC + i] + bv;
    float o[4];
#pragma unroll
    for (int c = 0; c < 4; ++c) o[c] = acc[a][c] + base + qq[b * NLQ + jt + tj * 4 + c];
    *(float4*)&Sb[(size_t)i * NLQ + jt + tj * 4] = *(float4*)o;
  }
}

// ---------------- row stats: masked max/sum over j (Lq=256) ----------------
__global__ __launch_bounds__(256) void k_rowstats(const float* __restrict__ S,
                                                  const int* __restrict__ Qmask,
                                                  float* __restrict__ rowmax,
                                                  float* __restrict__ rowsum) {
  const int tid = threadIdx.x;
  const int wv = tid >> 6, lane = tid & 63;
  const int row = blockIdx.x * 4 + wv;  // [0, NB*NLC)
  const int b = row >> 11;              // / NLC
  const float* Sr = S + (size_t)row * NLQ;
  const int* Qm = Qmask + b * NLQ;
  float v[4];
#pragma unroll
  for (int k = 0; k < 4; ++k) {
    int j = lane + k * 64;
    float s = Sr[j];
    v[k] = Qm[j] ? s : s + FNEG;
  }
  float mx = fmaxf(fmaxf(v[0], v[1]), fmaxf(v[2], v[3]));
#pragma unroll
  for (int off = 32; off > 0; off >>= 1) mx = fmaxf(mx, __shfl_xor(mx, off, 64));
  float sum = 0.f;
#pragma unroll
  for (int k = 0; k < 4; ++k) sum += expf(v[k] - mx);
#pragma unroll
  for (int off = 32; off > 0; off >>= 1) sum += __shfl_xor(sum, off, 64);
  if (lane == 0) {
    rowmax[row] = mx;
    rowsum[row] = sum;
  }
}

// ---------------- col stats: partial online logsumexp over i chunks --------
__global__ __launch_bounds__(256) void k_colpart(const float* __restrict__ S,
                                                 const int* __restrict__ Cmask,
                                                 float* __restrict__ pm,
                                                 float* __restrict__ ps) {
  __shared__ float sm[4][64];
  __shared__ float ss[4][64];
  const int b = blockIdx.z;
  const int jt = blockIdx.x * 64;
  const int ic0 = blockIdx.y * (NLC / 8);
  const int tid = threadIdx.x;
  const int isub = tid >> 6, jl = tid & 63;
  const float* Sb = S + (size_t)b * NLC * NLQ + jt + jl;
  const int* Cm = Cmask + b * NLC;
  float m = -3.4e38f, sum = 0.f;
  for (int i = ic0 + isub; i < ic0 + NLC / 8; i += 4) {
    float s = Sb[(size_t)i * NLQ];
    float v = Cm[i] ? s : s + FNEG;
    float nm = fmaxf(m, v);
    sum = sum * expf(m - nm) + expf(v - nm);
    m = nm;
  }
  sm[isub][jl] = m;
  ss[isub][jl] = sum;
  __syncthreads();
  if (isub == 0) {
    float M = sm[0][jl], Sm = ss[0][jl];
#pragma unroll
    for (int k = 1; k < 4; ++k) {
      float m2 = sm[k][jl], s2 = ss[k][jl];
      float nm = fmaxf(M, m2);
      Sm = Sm * expf(M - nm) + s2 * expf(m2 - nm);
      M = nm;
    }
    int j = b * NLQ + jt + jl;
    pm[j * 8 + blockIdx.y] = M;
    ps[j * 8 + blockIdx.y] = Sm;
  }
}

__global__ __launch_bounds__(256) void k_colcombine(const float* __restrict__ pm,
                                                    const float* __restrict__ ps,
                                                    float* __restrict__ colmax,
                                                    float* __restrict__ colsum) {
  int g = blockIdx.x * 256 + threadIdx.x;  // [0, NB*NLQ)
  float M = -3.4e38f, Sm = 0.f;
#pragma unroll
  for (int k = 0; k < 8; ++k) {
    float m2 = pm[g * 8 + k], s2 = ps[g * 8 + k];
    float nm = fmaxf(M, m2);
    Sm = Sm * expf(M - nm) + s2 * expf(m2 - nm);
    M = nm;
  }
  colmax[g] = M;
  colsum[g] = Sm;
}

// ---------------- MT[b,d,q] = sum_i S2[i,q] * C[b,d,i]  (bf16 out) ---------
__global__ __launch_bounds__(256) void k_MT(const float* __restrict__ C,
                                            const float* __restrict__ S,
                                            const int* __restrict__ Cmask,
                                            const float* __restrict__ colmax,
                                            const float* __restrict__ colsum,
                                            short* __restrict__ MT) {
  __shared__ float As[16][68];
  __shared__ float Ps[16][68];
  const int b = blockIdx.z;
  const int dt = blockIdx.x * 64;
  const int qt = blockIdx.y * 64;
  const int tid = threadIdx.x;
  const int ti = tid >> 4, tj = tid & 15;
  const float* Cb = C + (size_t)b * ND * NLC;
  const float* Sb = S + (size_t)b * NLC * NLQ;
  const int* Cm = Cmask + b * NLC;
  const float* cmx = colmax + b * NLQ + qt;
  float acc[4][4] = {};
  for (int i0 = 0; i0 < NLC; i0 += 16) {
#pragma unroll
    for (int k = 0; k < 4; ++k) {
      int idx = tid + k * 256;
      int kk = idx & 15, dd = idx >> 4;
      As[kk][dd] = Cb[(size_t)(dt + dd) * NLC + i0 + kk];
    }
#pragma unroll
    for (int k = 0; k < 4; ++k) {
      int idx = tid + k * 256;
      int qq = idx & 63, kk = idx >> 6;
      int i = i0 + kk;
      float s = Sb[(size_t)i * NLQ + qt + qq];
      float v = Cm[i] ? s : s + FNEG;
      Ps[kk][qq] = expf(v - cmx[qq]);
    }
    __syncthreads();
#pragma unroll
    for (int kk = 0; kk < 16; ++kk) {
      float a4[4], p4[4];
      *(float4*)a4 = *(const float4*)&As[kk][ti * 4];
      *(float4*)p4 = *(const float4*)&Ps[kk][tj * 4];
#pragma unroll
      for (int a = 0; a < 4; ++a)
#pragma unroll
        for (int c = 0; c < 4; ++c) acc[a][c] = fmaf(a4[a], p4[c], acc[a][c]);
    }
    __syncthreads();
  }
  const float* csm = colsum + b * NLQ + qt;
  float inv[4];
#pragma unroll
  for (int c = 0; c < 4; ++c) inv[c] = 1.0f / csm[tj * 4 + c];
  short* Mb = MT + (size_t)b * ND * NLQ;
#pragma unroll
  for (int a = 0; a < 4; ++a) {
    short4 o;
    o.x = f2bf(acc[a][0] * inv[0]);
    o.y = f2bf(acc[a][1] * inv[1]);
    o.z = f2bf(acc[a][2] * inv[2]);
    o.w = f2bf(acc[a][3] * inv[3]);
    *(short4*)&Mb[(size_t)(dt + ti * 4 + a) * NLQ + qt + tj * 4] = o;
  }
}

// ---------------- fused MFMA output ----------------------------------------
// Block: 256 thr = 4 waves; covers 64 Lc-rows (wave wi -> 16 rows), all 128 d.
// A-frag (per wave): S1 rows, built once in regs, reused by both phases.
// B-frag: Qbf / MTbf loaded directly from global (K=j contiguous).
// Epilogue: D-frags -> XOR-swizzled LDS transpose -> coalesced float4 stores.
__global__ __launch_bounds__(256) void k_out(const float* __restrict__ C,
                                             const float* __restrict__ S,
                                             const int* __restrict__ Qmask,
                                             const float* __restrict__ rowmax,
                                             const float* __restrict__ rowsum,
                                             const short* __restrict__ Qbf,
                                             const short* __restrict__ MTbf,
                                             float* __restrict__ out) {
  __shared__ float LT[128 * 64];
  const int b = blockIdx.y;
  const int it = blockIdx.x * 64;
  const int tid = threadIdx.x;
  const int wi = tid >> 6;            // wave -> i-subtile
  const int l = tid & 63;
  const int lm = l & 15, lk = l >> 4; // fragment lane indices
  const int row_i = it + wi * 16 + lm;

  // ---- build A fragments: S1 row chunks (masked exp, bf16) ----
  const float* Srow = S + ((size_t)b * NLC + row_i) * NLQ;
  const int* Qm = Qmask + b * NLQ;
  const float rmx = rowmax[b * NLC + row_i];
  bf16x8 afr[8];
#pragma unroll
  for (int kk = 0; kk < 8; ++kk) {
    const int j0 = kk * 32 + lk * 8;
    float sv[8];
    int qv[8];
    *(float4*)&sv[0] = *(const float4*)(Srow + j0);
    *(float4*)&sv[4] = *(const float4*)(Srow + j0 + 4);
    *(int4*)&qv[0] = *(const int4*)(Qm + j0);
    *(int4*)&qv[4] = *(const int4*)(Qm + j0 + 4);
    bf16x8 a;
#pragma unroll
    for (int c = 0; c < 8; ++c) a[c] = f2bf(qv[c] ? __expf(sv[c] - rmx) : 0.f);
    afr[kk] = a;
  }

  // ---- two GEMM phases over n-tiles of d ----
  f32x4 accA[8], accB[8];
  const short* Qb = Qbf + (size_t)b * ND * NLQ;
  const short* Mb = MTbf + (size_t)b * ND * NLQ;
#pragma unroll
  for (int n0 = 0; n0 < 8; ++n0) {
    const short* Bp = Qb + (size_t)(n0 * 16 + lm) * NLQ + lk * 8;
    f32x4 c = {0.f, 0.f, 0.f, 0.f};
#pragma unroll
    for (int kk = 0; kk < 8; ++kk)
      c = MFMA16(afr[kk], *(const bf16x8*)(Bp + kk * 32), c);
    accA[n0] = c;
  }
#pragma unroll
  for (int n0 = 0; n0 < 8; ++n0) {
    const short* Bp = Mb + (size_t)(n0 * 16 + lm) * NLQ + lk * 8;
    f32x4 c = {0.f, 0.f, 0.f, 0.f};
#pragma unroll
    for (int kk = 0; kk < 8; ++kk)
      c = MFMA16(afr[kk], *(const bf16x8*)(Bp + kk * 32), c);
    accB[n0] = c;
  }

  // ---- epilogue: scale rows by 1/rowsum, transpose via LDS, store ----
  float invs[4];
#pragma unroll
  for (int r = 0; r < 4; ++r)
    invs[r] = 1.0f / rowsum[b * NLC + it + wi * 16 + lk * 4 + r];

  const int dR = tid >> 1, ih = tid & 1;
  float Av[32], Bv[32];

  // phase A stage + read
#pragma unroll
  for (int n0 = 0; n0 < 8; ++n0) {
    const int d = n0 * 16 + lm;
    const int i4 = wi * 4 + lk;
    float* p = &LT[d * 64 + ((i4 ^ (d & 15)) << 2)];
#pragma unroll
    for (int r = 0; r < 4; ++r) p[r] = accA[n0][r] * invs[r];
  }
  __syncthreads();
#pragma unroll
  for (int s = 0; s < 8; ++s) {
    const int i4r = ih * 8 + s;
    *(float4*)&Av[s * 4] = *(const float4*)&LT[dR * 64 + ((i4r ^ (dR & 15)) << 2)];
  }
  __syncthreads();

  // phase B stage + read
#pragma unroll
  for (int n0 = 0; n0 < 8; ++n0) {
    const int d = n0 * 16 + lm;
    const int i4 = wi * 4 + lk;
    float* p = &LT[d * 64 + ((i4 ^ (d & 15)) << 2)];
#pragma unroll
    for (int r = 0; r < 4; ++r) p[r] = accB[n0][r] * invs[r];
  }
  __syncthreads();
#pragma unroll
  for (int s = 0; s < 8; ++s) {
    const int i4r = ih * 8 + s;
    *(float4*)&Bv[s * 4] = *(const float4*)&LT[dR * 64 + ((i4r ^ (dR & 15)) << 2)];
  }

  // coalesced writes: thread owns (d=dR, i-half=ih*32) of the 64-col tile
  const float* Crow = C + ((size_t)b * ND + dR) * NLC + it + ih * 32;
  float* ob = out + ((size_t)b * 4 * ND + dR) * NLC + it + ih * 32;
#pragma unroll
  for (int s = 0; s < 8; ++s) {
    float4 ct = *(const float4*)(Crow + s * 4);
    float4 av = *(float4*)&Av[s * 4];
    float4 bv = *(float4*)&Bv[s * 4];
    float4 ca, cb;
    ca.x = ct.x * av.x; ca.y = ct.y * av.y; ca.z = ct.z * av.z; ca.w = ct.w * av.w;
    cb.x = ct.x * bv.x; cb.y = ct.y * bv.y; cb.z = ct.z * bv.z; cb.w = ct.w * bv.w;
    *(float4*)(ob + s * 4) = ct;
    *(float4*)(ob + (size_t)128 * NLC + s * 4) = av;
    *(float4*)(ob + (size_t)256 * NLC + s * 4) = ca;
    *(float4*)(ob + (size_t)384 * NLC + s * 4) = cb;
  }
}

// ---------------------------------------------------------------------------
extern "C" void kernel_launch(void* const* d_in, const int* in_sizes, int n_in,
                              void* d_out, int out_size, void* d_ws, size_t ws_size,
                              hipStream_t stream) {
  const float* C = (const float*)d_in[0];
  const float* Q = (const float*)d_in[1];
  const int* Cmask = (const int*)d_in[2];
  const int* Qmask = (const int*)d_in[3];
  const float* w4C = (const float*)d_in[4];
  const float* w4Q = (const float*)d_in[5];
  const float* w4mlu = (const float*)d_in[6];
  const float* bias = (const float*)d_in[7];
  float* out = (float*)d_out;

  float* ws = (float*)d_ws;
  float* S = ws;
  float* rowmax = S + (size_t)NB * NLC * NLQ;
  float* rowsum = rowmax + NB * NLC;
  float* colmax = rowsum + NB * NLC;
  float* colsum = colmax + NB * NLQ;
  float* MTslot = colsum + NB * NLQ;          // NB*ND*NLQ floats reserved
  short* MTbf = (short*)MTslot;               // uses half the slot
  float* cq = MTslot + (size_t)NB * ND * NLQ;
  float* qq = cq + NB * NLC;
  float* pm = qq + NB * NLQ;
  float* ps = pm + NB * NLQ * 8;
  short* Qbf = (short*)(ps + NB * NLQ * 8);   // NB*ND*NLQ shorts
  size_t need = (size_t)((float*)Qbf - ws) * sizeof(float) + (size_t)NB * ND * NLQ * sizeof(short);
  if (ws_size < need) return;  // fail loudly (output stays zero) rather than corrupt

  k_cq<<<NB * NLC / 256, 256, 0, stream>>>(C, w4C, cq, NLC);
  k_cq<<<NB * NLQ / 256, 256, 0, stream>>>(Q, w4Q, qq, NLQ);
  k_cvt<<<NB * ND * NLQ / 1024, 256, 0, stream>>>(Q, Qbf);
  k_S<<<dim3(NLC / 64, NLQ / 64, NB), 256, 0, stream>>>(C, Q, w4mlu, cq, qq, bias, S);
  k_rowstats<<<NB * NLC / 4, 256, 0, stream>>>(S, Qmask, rowmax, rowsum);
  k_colpart<<<dim3(NLQ / 64, 8, NB), 256, 0, stream>>>(S, Cmask, pm, ps);
  k_colcombine<<<NB * NLQ / 256, 256, 0, stream>>>(pm, ps, colmax, colsum);
  k_MT<<<dim3(ND / 64, NLQ / 64, NB), 256, 0, stream>>>(C, S, Cmask, colmax, colsum, MTbf);
  k_out<<<dim3(NLC / 64, NB), 256, 0, stream>>>(C, S, Qmask, rowmax, rowsum, Qbf, MTbf, out);
}

// Round 3
// 305.358 us; speedup vs baseline: 2.1879x; 1.5395x over previous
//
#include <hip/hip_runtime.h>
#include <cstdint>

// CQAttention: B=32, D=128, Lc=2048, Lq=256, f32 in/out.
// Recompute-S pipeline (S never materialized):
//   k_cq x2 : cq = Ct@w4C, qq = Qt@w4Q
//   k_tr x2 : bf16 copies: Ct_bf [b][i][d], Cbf [b][d][i],
//             Qtw [b][j][d] (w4mlu folded), Qbf [b][d][j]
//   k_MT    : 2-pass. pass1: S^T tiles via MFMA -> colmax (block-local).
//             pass2: S^T + exp -> LDS P^T -> MT = P2^T-weighted C, /colsum.
//   k_out   : S tile via MFMA -> row softmax (block-local) -> P1 in LDS ->
//             A = S1@Qt, Bt = S1@MT (MFMA) -> [Ct, A, Ct*A, Ct*Bt] stores.
// Bt = S1 @ (S2^T @ Ct) associativity rewrite avoids the Lc x Lc matrix.

#define NB 32
#define ND 128
#define NLC 2048
#define NLQ 256
#define FNEG (-1.0e30f)

typedef __attribute__((ext_vector_type(8))) short bf16x8;
typedef __attribute__((ext_vector_type(4))) float f32x4;
#define MFMA16(a, b, c) __builtin_amdgcn_mfma_f32_16x16x32_bf16(a, b, c, 0, 0, 0)

__device__ __forceinline__ short f2bf(float x) {
  union { float f; unsigned u; } v; v.f = x;
  unsigned r = (v.u + 0x7FFFu + ((v.u >> 16) & 1u)) >> 16;
  return (short)r;
}

// ---------------- cq / qq : out[g] = sum_d In[b,d,i] * w[d] ----------------
__global__ __launch_bounds__(256) void k_cq(const float* __restrict__ In,
                                            const float* __restrict__ w,
                                            float* __restrict__ outv, int L) {
  int g = blockIdx.x * 256 + threadIdx.x;
  int b = g / L, i = g - b * L;
  const float* p = In + (size_t)b * ND * L + i;
  float s = 0.f;
#pragma unroll 16
  for (int d = 0; d < ND; ++d) s = fmaf(p[(size_t)d * L], w[d], s);
  outv[g] = s;
}

// ---------------- bf16 copies: transposed (scaled) + natural ---------------
// in [b][ND][L] f32 -> outT [b][L][ND] bf16 (x wvec[d] if wvec), outN [b][ND][L] bf16
__global__ __launch_bounds__(256) void k_tr(const float* __restrict__ in,
                                            const float* __restrict__ wvec,
                                            short* __restrict__ outT,
                                            short* __restrict__ outN, int L) {
  __shared__ float T[32][66];
  const int b = blockIdx.z, d0 = blockIdx.y * 32, i0 = blockIdx.x * 64;
  const int t = threadIdx.x;
#pragma unroll
  for (int rr = 0; rr < 2; ++rr) {
    int idx = t + rr * 256;
    int dd = idx >> 4, c4 = idx & 15;
    const float* src = in + ((size_t)b * ND + d0 + dd) * L + i0 + c4 * 4;
    float4 v = *(const float4*)src;
    T[dd][c4 * 4 + 0] = v.x;
    T[dd][c4 * 4 + 1] = v.y;
    T[dd][c4 * 4 + 2] = v.z;
    T[dd][c4 * 4 + 3] = v.w;
    if (outN) {
      short4 o;
      o.x = f2bf(v.x); o.y = f2bf(v.y); o.z = f2bf(v.z); o.w = f2bf(v.w);
      *(short4*)(outN + ((size_t)b * ND + d0 + dd) * L + i0 + c4 * 4) = o;
    }
  }
  __syncthreads();
  const int i = t >> 2, seg = t & 3;
  bf16x8 pack;
#pragma unroll
  for (int k = 0; k < 8; ++k) {
    int d = seg * 8 + k;
    float x = T[d][i];
    if (wvec) x *= wvec[d0 + d];
    pack[k] = f2bf(x);
  }
  *(bf16x8*)(outT + ((size_t)b * L + i0 + i) * ND + d0 + seg * 8) = pack;
}

// ---------------- k_MT: MT[b,d,q] = sum_i softmax_col(S)[i,q] * C[b,d,i] ---
// grid (NLQ/32, NB), 512 thr (8 waves). Full d=128, full i loop per block.
__global__ __launch_bounds__(512) void k_MT(const short* __restrict__ Ctbf,
                                            const short* __restrict__ Qtw,
                                            const short* __restrict__ Cbf,
                                            const int* __restrict__ Cmask,
                                            const float* __restrict__ cq,
                                            const float* __restrict__ qq,
                                            const float* __restrict__ bias,
                                            short* __restrict__ MTbf) {
  __shared__ short PTs[32 * 136];   // P2^T bf16 [q 32][i-chunk 128], pad->136
  __shared__ float cspart[8][32];
  __shared__ float bc[32];
  const int b = blockIdx.y, qt = blockIdx.x * 32;
  const int tid = threadIdx.x;
  const int w = tid >> 6, l = tid & 63, lm = l & 15, lk = l >> 4;
  const int qsub = w & 1, ipair = w >> 1;
  const float bv = bias[0];

  // hoisted A-frags (Q side): A[m=q][k=d]
  bf16x8 aq[4];
  const short* Qrow = Qtw + ((size_t)b * NLQ + qt + qsub * 16 + lm) * ND + lk * 8;
#pragma unroll
  for (int kk = 0; kk < 4; ++kk) aq[kk] = *(const bf16x8*)(Qrow + kk * 32);
  float qqv[4];
#pragma unroll
  for (int r = 0; r < 4; ++r) qqv[r] = qq[b * NLQ + qt + qsub * 16 + lk * 4 + r];

  // ---- pass 1: colmax over i ----
  float cmax[4] = {-3.4e38f, -3.4e38f, -3.4e38f, -3.4e38f};
  for (int i0 = 0; i0 < NLC; i0 += 128) {
#pragma unroll
    for (int t2 = 0; t2 < 2; ++t2) {
      const int isub = ipair * 2 + t2;
      const int iCol = i0 + isub * 16 + lm;
      const short* Crow = Ctbf + ((size_t)b * NLC + iCol) * ND + lk * 8;
      f32x4 c = {0.f, 0.f, 0.f, 0.f};
#pragma unroll
      for (int kk = 0; kk < 4; ++kk)
        c = MFMA16(aq[kk], *(const bf16x8*)(Crow + kk * 32), c);
      const float cqb = cq[b * NLC + iCol] + bv;
      const int cm = Cmask[b * NLC + iCol];
#pragma unroll
      for (int r = 0; r < 4; ++r) {
        float s = c[r] + cqb + qqv[r];
        float v = cm ? s : s + FNEG;
        cmax[r] = fmaxf(cmax[r], v);
      }
    }
  }
#pragma unroll
  for (int off = 1; off < 16; off <<= 1)
#pragma unroll
    for (int r = 0; r < 4; ++r) cmax[r] = fmaxf(cmax[r], __shfl_xor(cmax[r], off, 64));
  if (lm == 0) {
#pragma unroll
    for (int r = 0; r < 4; ++r) cspart[w][qsub * 16 + lk * 4 + r] = cmax[r];
  }
  __syncthreads();
  if (tid < 32) {
    const int base = (tid >> 4) & 1;
    float m = -3.4e38f;
#pragma unroll
    for (int k2 = 0; k2 < 4; ++k2) m = fmaxf(m, cspart[k2 * 2 + base][tid]);
    bc[tid] = m;
  }
  __syncthreads();
  float cmr[4];
#pragma unroll
  for (int r = 0; r < 4; ++r) cmr[r] = bc[qsub * 16 + lk * 4 + r];
  __syncthreads();

  // ---- pass 2: exp -> LDS P^T, MT GEMM, colsum ----
  float csacc[4] = {0.f, 0.f, 0.f, 0.f};
  f32x4 accMT[2] = {{0.f, 0.f, 0.f, 0.f}, {0.f, 0.f, 0.f, 0.f}};
  for (int i0 = 0; i0 < NLC; i0 += 128) {
#pragma unroll
    for (int t2 = 0; t2 < 2; ++t2) {
      const int isub = ipair * 2 + t2;
      const int iCol = i0 + isub * 16 + lm;
      const short* Crow = Ctbf + ((size_t)b * NLC + iCol) * ND + lk * 8;
      f32x4 c = {0.f, 0.f, 0.f, 0.f};
#pragma unroll
      for (int kk = 0; kk < 4; ++kk)
        c = MFMA16(aq[kk], *(const bf16x8*)(Crow + kk * 32), c);
      const float cqb = cq[b * NLC + iCol] + bv;
      const int cm = Cmask[b * NLC + iCol];
#pragma unroll
      for (int r = 0; r < 4; ++r) {
        float s = c[r] + cqb + qqv[r];
        float v = cm ? s : s + FNEG;
        float p = __expf(v - cmr[r]);
        csacc[r] += p;
        PTs[(qsub * 16 + lk * 4 + r) * 136 + isub * 16 + lm] = f2bf(p);
      }
    }
    __syncthreads();
    // MT GEMM: A[m=d]=Cbf (i-contig), B[k=i][n=q]=P^T from LDS
    const short* Arow = Cbf + ((size_t)b * ND + w * 16 + lm) * NLC + i0 + lk * 8;
#pragma unroll
    for (int ks = 0; ks < 4; ++ks) {
      bf16x8 a = *(const bf16x8*)(Arow + ks * 32);
#pragma unroll
      for (int qs = 0; qs < 2; ++qs) {
        bf16x8 bb = *(const bf16x8*)&PTs[(qs * 16 + lm) * 136 + ks * 32 + lk * 8];
        accMT[qs] = MFMA16(a, bb, accMT[qs]);
      }
    }
    __syncthreads();
  }
  // colsum reduce
#pragma unroll
  for (int off = 1; off < 16; off <<= 1)
#pragma unroll
    for (int r = 0; r < 4; ++r) csacc[r] += __shfl_xor(csacc[r], off, 64);
  if (lm == 0) {
#pragma unroll
    for (int r = 0; r < 4; ++r) cspart[w][qsub * 16 + lk * 4 + r] = csacc[r];
  }
  __syncthreads();
  if (tid < 32) {
    const int base = (tid >> 4) & 1;
    float s = 0.f;
#pragma unroll
    for (int k2 = 0; k2 < 4; ++k2) s += cspart[k2 * 2 + base][tid];
    bc[tid] = 1.0f / s;
  }
  __syncthreads();
#pragma unroll
  for (int qs = 0; qs < 2; ++qs) {
    const float inv = bc[qs * 16 + lm];
#pragma unroll
    for (int r = 0; r < 4; ++r)
      MTbf[((size_t)b * ND + w * 16 + lk * 4 + r) * NLQ + qt + qs * 16 + lm] =
          f2bf(accMT[qs][r] * inv);
  }
}

// ---------------- k_out: recompute S, row softmax, A/Bt GEMMs, stores ------
// grid (NLC/64, NB), 256 thr (4 waves). Wave wi -> 16 i-rows.
__global__ __launch_bounds__(256) void k_out(const float* __restrict__ C,
                                             const short* __restrict__ Ctbf,
                                             const short* __restrict__ Qtw,
                                             const short* __restrict__ Qbf,
                                             const short* __restrict__ MTbf,
                                             const int* __restrict__ Qmask,
                                             const float* __restrict__ cq,
                                             const float* __restrict__ qq,
                                             const float* __restrict__ bias,
                                             float* __restrict__ out) {
  __shared__ __align__(16) char SMEM[64 * 264 * 2];  // P1 bf16 [64][264]; later LT f32
  short* PTs = (short*)SMEM;
  float* LT = (float*)SMEM;
  const int b = blockIdx.y;
  const int it = blockIdx.x * 64;
  const int tid = threadIdx.x;
  const int wi = tid >> 6, l = tid & 63, lm = l & 15, lk = l >> 4;

  // ---- phase 0: S tile [64 x 256] via MFMA ----
  bf16x8 aS[4];
  {
    const short* Crow = Ctbf + ((size_t)b * NLC + it + wi * 16 + lm) * ND + lk * 8;
#pragma unroll
    for (int kk = 0; kk < 4; ++kk) aS[kk] = *(const bf16x8*)(Crow + kk * 32);
  }
  f32x4 accS[16];
#pragma unroll
  for (int js = 0; js < 16; ++js) {
    const short* Qrow = Qtw + ((size_t)b * NLQ + js * 16 + lm) * ND + lk * 8;
    f32x4 c = {0.f, 0.f, 0.f, 0.f};
#pragma unroll
    for (int kk = 0; kk < 4; ++kk)
      c = MFMA16(aS[kk], *(const bf16x8*)(Qrow + kk * 32), c);
    accS[js] = c;
  }
  const float bv = bias[0];
  float cqb[4];
#pragma unroll
  for (int r = 0; r < 4; ++r) cqb[r] = cq[b * NLC + it + wi * 16 + lk * 4 + r] + bv;
  float rmax[4] = {-3.4e38f, -3.4e38f, -3.4e38f, -3.4e38f};
#pragma unroll
  for (int js = 0; js < 16; ++js) {
    const int j = js * 16 + lm;
    const float qv = qq[b * NLQ + j];
    const int qm = Qmask[b * NLQ + j];
#pragma unroll
    for (int r = 0; r < 4; ++r) {
      float s = accS[js][r] + cqb[r] + qv;
      float v = qm ? s : s + FNEG;
      accS[js][r] = v;
      rmax[r] = fmaxf(rmax[r], v);
    }
  }
#pragma unroll
  for (int off = 1; off < 16; off <<= 1)
#pragma unroll
    for (int r = 0; r < 4; ++r) rmax[r] = fmaxf(rmax[r], __shfl_xor(rmax[r], off, 64));
  float rsum[4] = {0.f, 0.f, 0.f, 0.f};
#pragma unroll
  for (int js = 0; js < 16; ++js) {
#pragma unroll
    for (int r = 0; r < 4; ++r) {
      float p = __expf(accS[js][r] - rmax[r]);
      rsum[r] += p;
      PTs[(wi * 16 + lk * 4 + r) * 264 + js * 16 + lm] = f2bf(p);
    }
  }
#pragma unroll
  for (int off = 1; off < 16; off <<= 1)
#pragma unroll
    for (int r = 0; r < 4; ++r) rsum[r] += __shfl_xor(rsum[r], off, 64);
  float invr[4];
#pragma unroll
  for (int r = 0; r < 4; ++r) invr[r] = 1.0f / rsum[r];
  __syncthreads();

  // ---- A-frags from LDS (P1 rows, j-contiguous) ----
  bf16x8 afr[8];
#pragma unroll
  for (int kk = 0; kk < 8; ++kk)
    afr[kk] = *(const bf16x8*)&PTs[(wi * 16 + lm) * 264 + kk * 32 + lk * 8];
  __syncthreads();  // all PTs reads done before LT overwrite

  // ---- two GEMM phases over n-tiles of d ----
  f32x4 accA[8], accB[8];
  const short* Qb = Qbf + (size_t)b * ND * NLQ;
  const short* Mb = MTbf + (size_t)b * ND * NLQ;
#pragma unroll
  for (int n0 = 0; n0 < 8; ++n0) {
    const short* Bp = Qb + (size_t)(n0 * 16 + lm) * NLQ + lk * 8;
    f32x4 c = {0.f, 0.f, 0.f, 0.f};
#pragma unroll
    for (int kk = 0; kk < 8; ++kk)
      c = MFMA16(afr[kk], *(const bf16x8*)(Bp + kk * 32), c);
    accA[n0] = c;
  }
#pragma unroll
  for (int n0 = 0; n0 < 8; ++n0) {
    const short* Bp = Mb + (size_t)(n0 * 16 + lm) * NLQ + lk * 8;
    f32x4 c = {0.f, 0.f, 0.f, 0.f};
#pragma unroll
    for (int kk = 0; kk < 8; ++kk)
      c = MFMA16(afr[kk], *(const bf16x8*)(Bp + kk * 32), c);
    accB[n0] = c;
  }

  // ---- epilogue: scale by 1/rowsum, transpose via LDS, coalesced stores ----
  const int dR = tid >> 1, ih = tid & 1;
  float Av[32], Bv[32];
#pragma unroll
  for (int n0 = 0; n0 < 8; ++n0) {
    const int d = n0 * 16 + lm;
    const int i4 = wi * 4 + lk;
    float* p = &LT[d * 64 + ((i4 ^ (d & 15)) << 2)];
#pragma unroll
    for (int r = 0; r < 4; ++r) p[r] = accA[n0][r] * invr[r];
  }
  __syncthreads();
#pragma unroll
  for (int s = 0; s < 8; ++s) {
    const int i4r = ih * 8 + s;
    *(float4*)&Av[s * 4] = *(const float4*)&LT[dR * 64 + ((i4r ^ (dR & 15)) << 2)];
  }
  __syncthreads();
#pragma unroll
  for (int n0 = 0; n0 < 8; ++n0) {
    const int d = n0 * 16 + lm;
    const int i4 = wi * 4 + lk;
    float* p = &LT[d * 64 + ((i4 ^ (d & 15)) << 2)];
#pragma unroll
    for (int r = 0; r < 4; ++r) p[r] = accB[n0][r] * invr[r];
  }
  __syncthreads();
#pragma unroll
  for (int s = 0; s < 8; ++s) {
    const int i4r = ih * 8 + s;
    *(float4*)&Bv[s * 4] = *(const float4*)&LT[dR * 64 + ((i4r ^ (dR & 15)) << 2)];
  }

  const float* Crow = C + ((size_t)b * ND + dR) * NLC + it + ih * 32;
  float* ob = out + ((size_t)b * 4 * ND + dR) * NLC + it + ih * 32;
#pragma unroll
  for (int s = 0; s < 8; ++s) {
    float4 ct = *(const float4*)(Crow + s * 4);
    float4 av = *(float4*)&Av[s * 4];
    float4 bv4 = *(float4*)&Bv[s * 4];
    float4 ca, cb;
    ca.x = ct.x * av.x; ca.y = ct.y * av.y; ca.z = ct.z * av.z; ca.w = ct.w * av.w;
    cb.x = ct.x * bv4.x; cb.y = ct.y * bv4.y; cb.z = ct.z * bv4.z; cb.w = ct.w * bv4.w;
    *(float4*)(ob + s * 4) = ct;
    *(float4*)(ob + (size_t)128 * NLC + s * 4) = av;
    *(float4*)(ob + (size_t)256 * NLC + s * 4) = ca;
    *(float4*)(ob + (size_t)384 * NLC + s * 4) = cb;
  }
}

// ---------------------------------------------------------------------------
extern "C" void kernel_launch(void* const* d_in, const int* in_sizes, int n_in,
                              void* d_out, int out_size, void* d_ws, size_t ws_size,
                              hipStream_t stream) {
  const float* C = (const float*)d_in[0];
  const float* Q = (const float*)d_in[1];
  const int* Cmask = (const int*)d_in[2];
  const int* Qmask = (const int*)d_in[3];
  const float* w4C = (const float*)d_in[4];
  const float* w4Q = (const float*)d_in[5];
  const float* w4mlu = (const float*)d_in[6];
  const float* bias = (const float*)d_in[7];
  float* out = (float*)d_out;

  short* Ctbf = (short*)d_ws;                          // [b][Lc][D]
  short* Cbf = Ctbf + (size_t)NB * NLC * ND;           // [b][D][Lc]
  short* Qtw = Cbf + (size_t)NB * NLC * ND;            // [b][Lq][D] (w4mlu folded)
  short* Qbf = Qtw + (size_t)NB * NLQ * ND;            // [b][D][Lq]
  short* MTbf = Qbf + (size_t)NB * NLQ * ND;           // [b][D][Lq]
  float* cq = (float*)(MTbf + (size_t)NB * ND * NLQ);
  float* qq = cq + NB * NLC;
  size_t need = (size_t)(qq + NB * NLQ - (float*)d_ws) * sizeof(float);
  if (ws_size < need) return;  // fail loudly rather than corrupt

  k_cq<<<NB * NLC / 256, 256, 0, stream>>>(C, w4C, cq, NLC);
  k_cq<<<NB * NLQ / 256, 256, 0, stream>>>(Q, w4Q, qq, NLQ);
  k_tr<<<dim3(NLC / 64, ND / 32, NB), 256, 0, stream>>>(C, nullptr, Ctbf, Cbf, NLC);
  k_tr<<<dim3(NLQ / 64, ND / 32, NB), 256, 0, stream>>>(Q, w4mlu, Qtw, Qbf, NLQ);
  k_MT<<<dim3(NLQ / 32, NB), 512, 0, stream>>>(Ctbf, Qtw, Cbf, Cmask, cq, qq, bias, MTbf);
  k_out<<<dim3(NLC / 64, NB), 256, 0, stream>>>(C, Ctbf, Qtw, Qbf, MTbf, Qmask, cq, qq, bias, out);
}